// Round 7
// baseline (336.565 us; speedup 1.0000x reference)
//
#include <hip/hip_runtime.h>
#include <math.h>

#define NUM_IN 1024
#define TILE_R 8                     // rows per tile (32 KB f32)
#define T4R (TILE_R * NUM_IN / 4)    // 2048 float4 per tile
#define NB_MAX 512

using bf16x8 = __attribute__((ext_vector_type(8))) short;
using f32x4  = __attribute__((ext_vector_type(4))) float;

__device__ __forceinline__ unsigned int f2bf1(float f) {
  unsigned int u = __float_as_uint(f);
  return (u + 0x7fffu + ((u >> 16) & 1u)) >> 16;   // RNE f32 -> bf16
}
__device__ __forceinline__ unsigned int pk2(float a, float b) {
  return f2bf1(a) | (f2bf1(b) << 16);
}
__device__ __forceinline__ float bf2f(unsigned int s) {
  return __uint_as_float(s << 16);
}

// barrier draining LDS ops only — global loads stay in flight
#define BARX() do { \
  __builtin_amdgcn_sched_barrier(0); \
  asm volatile("s_waitcnt lgkmcnt(0)" ::: "memory"); \
  __builtin_amdgcn_s_barrier(); \
  __builtin_amdgcn_sched_barrier(0); \
} while (0)

#define WAIT_VM0() do { \
  __builtin_amdgcn_sched_barrier(0); \
  asm volatile("s_waitcnt vmcnt(0)" ::: "memory"); \
  __builtin_amdgcn_sched_barrier(0); \
} while (0)

// 512 blocks x 512 threads (8 waves) -> 2 blocks/CU (LDS 37 KB, VGPR<=128).
// Wave w: n-tile nt=w&3, K-half kh=w>>2. 8-row tile, single-buffered bf16 xt
// (rows 8-15 zeroed once for the 16-row MFMA A-fragment). Register staging:
// tile T+1 issued top of iter T, drained top of iter T+1. Cross-block overlap
// (2 independent barrier groups per CU) keeps HBM fed through serial phases.
__global__ __launch_bounds__(512, 4) void ga_main(
    const float* __restrict__ x,
    const float* __restrict__ Vw, const float* __restrict__ Uw,
    const float* __restrict__ Vb, const float* __restrict__ Ub,
    const float* __restrict__ ww, const float* __restrict__ wb,
    float* __restrict__ wsAcc, float* __restrict__ wsM, float* __restrict__ wsS,
    int nb, int nTiles)
{
  __shared__ __align__(16) unsigned short xt[16 * NUM_IN];   // 32 KB (rows 8-15 stay zero)
  __shared__ __align__(16) float prered[TILE_R][2][64];      // 4 KB
  __shared__ __align__(16) float lgs[TILE_R];

  const int tid = threadIdx.x;
  const int b   = blockIdx.x;
  const int w   = tid >> 6;
  const int l   = tid & 63;
  const int l15 = l & 15;
  const int kg  = l >> 4;
  const int nt  = w & 3;
  const int kh  = w >> 2;
  const int h   = tid & 31;
  const int rr  = tid >> 5;      // row for act phase (tid<256)
  char* xbase = (char*)xt;

  const float vbh = Vb[h], ubh = Ub[h], wwh = ww[h];
  const float wb0 = wb[0];

  // ---- weights: bf16 B-fragments for (nt, kh): 16 x uint4 = 64 VGPR ----
  // lane holds col o = nt*16 + l15; k = kh*512 + s*32 + kg*8 + i
  uint4 bfr[16];
  {
    const int o = (nt << 4) + l15;
    const float* Wr = (o < 32) ? (Vw + (size_t)o * NUM_IN) : (Uw + (size_t)(o - 32) * NUM_IN);
    #pragma unroll
    for (int s = 0; s < 16; ++s) {
      const int k0 = (kh << 9) + (s << 5) + (kg << 3);
      const float4 a = *reinterpret_cast<const float4*>(Wr + k0);
      const float4 c = *reinterpret_cast<const float4*>(Wr + k0 + 4);
      uint4 v;
      v.x = pk2(a.x, a.y); v.y = pk2(a.z, a.w);
      v.z = pk2(c.x, c.y); v.w = pk2(c.z, c.w);
      bfr[s] = v;
    }
    #pragma unroll
    for (int s = 0; s < 16; ++s)   // 32-bit tied anchors: keep weights resident
      asm volatile("" : "+v"(bfr[s].x), "+v"(bfr[s].y), "+v"(bfr[s].z), "+v"(bfr[s].w));
  }

  const float4* xg = reinterpret_cast<const float4*>(x);
  float4 stg[4];                  // 16 VGPR staging (64 B/thread = 32 KB/block)

  #define ISSUE(Tt) do { \
    _Pragma("unroll") \
    for (int j = 0; j < 4; ++j) stg[j] = xg[(size_t)(Tt) * T4R + (j << 9) + tid]; \
  } while (0)

  // staged f32 -> swizzled bf16 (rows 0-7); thread's 4 float4 are rows idx>>8
  #define CONVERT() do { \
    _Pragma("unroll") \
    for (int j = 0; j < 4; ++j) { \
      const int idx = (j << 9) + tid; \
      const int row = idx >> 8; \
      const int col8 = (idx & 255) << 3; \
      uint2 v; v.x = pk2(stg[j].x, stg[j].y); v.y = pk2(stg[j].z, stg[j].w); \
      *reinterpret_cast<uint2*>(xbase + ((row << 11) + (col8 ^ ((row & 7) << 4)))) = v; \
    } \
  } while (0)

  float M = -INFINITY, S = 0.f;
  float aX = 0.f, aY = 0.f;
  int T = b;

  // ---- prologue: issue tile b; zero MFMA rows 8-15 (16 KB) ----
  ISSUE(T);
  {
    const uint4 z = {0u, 0u, 0u, 0u};
    *reinterpret_cast<uint4*>(xbase + 16384 + (tid << 4)) = z;
    *reinterpret_cast<uint4*>(xbase + 24576 + (tid << 4)) = z;
  }

  while (true) {
    const bool more = (T + nb) < nTiles;

    // ---- convert tile T, issue T+1 (drains next iteration) ----
    WAIT_VM0();
    CONVERT();
    if (more) ISSUE(T + nb);
    BARX();   // xt ready (also publishes prologue zeros on iter 0)

    // ---- MFMA: partial logits for (nt, kh); rows 8-15 are zero padding ----
    {
      f32x4 acc = {0.f, 0.f, 0.f, 0.f};
      #pragma unroll
      for (int s = 0; s < 16; ++s) {
        const int aoff = (l15 << 11) + ((((kh << 10) + (s << 6) + (kg << 4))) ^ ((l15 & 7) << 4));
        const bf16x8 af = *reinterpret_cast<const bf16x8*>(xbase + aoff);
        acc = __builtin_amdgcn_mfma_f32_16x16x32_bf16(af, __builtin_bit_cast(bf16x8, bfr[s]), acc, 0, 0, 0);
      }
      if (kg < 2) {   // rows 0-7 only (row = kg*4 + r)
        #pragma unroll
        for (int r = 0; r < 4; ++r)
          prered[(kg << 2) + r][kh][(nt << 4) + l15] = acc[r];
      }
    }
    BARX();

    // ---- activations + per-row logit (256 threads = 8 rows x 32 h) ----
    if (tid < 256) {
      const float pv = prered[rr][0][h] + prered[rr][1][h] + vbh;
      const float pu = prered[rr][0][32 + h] + prered[rr][1][32 + h] + ubh;
      const float ev = __expf(2.f * pv);
      const float av = (ev - 1.f) * __builtin_amdgcn_rcpf(ev + 1.f);   // tanh
      const float au = __builtin_amdgcn_rcpf(1.f + __expf(-pu));       // sigmoid
      float g = av * au * wwh;
      g += __shfl_xor(g, 1);
      g += __shfl_xor(g, 2);
      g += __shfl_xor(g, 4);
      g += __shfl_xor(g, 8);
      g += __shfl_xor(g, 16);
      if (h == 0) lgs[rr] = g + wb0;
    }
    BARX();

    // ---- Phase B: online softmax + weighted accumulation (col pair = tid) ----
    {
      float lf[8];
      #pragma unroll
      for (int j = 0; j < 8; ++j) lf[j] = lgs[j];
      float mc = lf[0];
      #pragma unroll
      for (int j = 1; j < 8; ++j) mc = fmaxf(mc, lf[j]);
      const float newM = fmaxf(M, mc);
      const float scale = __expf(M - newM);
      S *= scale; aX *= scale; aY *= scale;
      #pragma unroll
      for (int j = 0; j < 8; ++j) {
        const float p = __expf(lf[j] - newM);
        S += p;
        const unsigned int xv = *reinterpret_cast<const unsigned int*>(
            xbase + (j << 11) + (((tid << 2)) ^ ((j & 7) << 4)));
        aX += p * bf2f(xv & 0xffffu);
        aY += p * bf2f(xv >> 16);
      }
      M = newM;
    }
    BARX();   // xt free for next convert

    if (!more) break;
    T += nb;
  }

  *reinterpret_cast<float2*>(&wsAcc[(size_t)b * NUM_IN + (tid << 1)]) = make_float2(aX, aY);
  if (tid == 0) { wsM[b] = M; wsS[b] = S; }
}

// stage 1: global max M, weights wg_i = exp(M_i - M), total S -> wsT[0]=S
__global__ void ga_reduceMS(const float* __restrict__ wsM, const float* __restrict__ wsS,
                            float* __restrict__ wsW, float* __restrict__ wsT, int nb)
{
  __shared__ float sm[8], ss[8];
  const int t = threadIdx.x;   // 512
  float m = (t < nb) ? wsM[t] : -INFINITY;
  float mm = m;
  #pragma unroll
  for (int d = 1; d < 64; d <<= 1) mm = fmaxf(mm, __shfl_xor(mm, d));
  if ((t & 63) == 0) sm[t >> 6] = mm;
  __syncthreads();
  const float M = fmaxf(fmaxf(fmaxf(sm[0], sm[1]), fmaxf(sm[2], sm[3])),
                        fmaxf(fmaxf(sm[4], sm[5]), fmaxf(sm[6], sm[7])));
  const float wg = (t < nb) ? __expf(m - M) : 0.f;
  if (t < nb) wsW[t] = wg;
  float s = wg * ((t < nb) ? wsS[t] : 0.f);
  #pragma unroll
  for (int d = 1; d < 64; d <<= 1) s += __shfl_xor(s, d);
  if ((t & 63) == 0) ss[t >> 6] = s;
  __syncthreads();
  if (t == 0) {
    float St = 0.f;
    #pragma unroll
    for (int k = 0; k < 8; ++k) St += ss[k];
    wsT[0] = St;
  }
}

// stage 2: out[col] = (sum_i wg_i * wsAcc[i][col]) / S. 32 blocks x 32 cols.
__global__ void ga_combine(const float* __restrict__ wsAcc, const float* __restrict__ wsW,
                           const float* __restrict__ wsT, float* __restrict__ out, int nb)
{
  __shared__ float red[8][32];
  const int t = threadIdx.x;                    // 256
  const int col = (blockIdx.x << 5) + (t & 31);
  const int seg = t >> 5;                       // 0..7
  float s = 0.f;
  for (int ii = 0; ii < 64; ++ii) {
    const int i = (seg << 6) + ii;
    if (i < nb) s = fmaf(wsW[i], wsAcc[(size_t)i * NUM_IN + col], s);
  }
  red[seg][t & 31] = s;
  __syncthreads();
  if (seg == 0) {
    float tot = 0.f;
    #pragma unroll
    for (int k = 0; k < 8; ++k) tot += red[k][t];
    out[col] = tot / wsT[0];
  }
}

extern "C" void kernel_launch(void* const* d_in, const int* in_sizes, int n_in,
                              void* d_out, int out_size, void* d_ws, size_t ws_size,
                              hipStream_t stream)
{
  const float* x  = (const float*)d_in[0];
  const float* Vw = (const float*)d_in[1];
  const float* Vb = (const float*)d_in[2];
  const float* Uw = (const float*)d_in[3];
  const float* Ub = (const float*)d_in[4];
  const float* ww = (const float*)d_in[5];
  const float* wb = (const float*)d_in[6];
  float* out = (float*)d_out;

  const int Nrows  = in_sizes[0] / NUM_IN;   // 200000
  const int nTiles = Nrows / TILE_R;         // 25000

  const size_t per = (size_t)NUM_IN * 4 + 16;   // acc + M,S,W (+pad)
  int nb = (int)((ws_size - 64) / per);
  if (nb > NB_MAX)  nb = NB_MAX;
  if (nb > nTiles)  nb = nTiles;
  if (nb < 1)       nb = 1;

  float* wsAcc = (float*)d_ws;
  float* wsM   = wsAcc + (size_t)nb * NUM_IN;
  float* wsS   = wsM + nb;
  float* wsW   = wsS + nb;
  float* wsT   = wsW + nb;

  ga_main<<<nb, 512, 0, stream>>>(x, Vw, Uw, Vb, Ub, ww, wb, wsAcc, wsM, wsS, nb, nTiles);
  ga_reduceMS<<<1, 512, 0, stream>>>(wsM, wsS, wsW, wsT, nb);
  ga_combine<<<32, 256, 0, stream>>>(wsAcc, wsW, wsT, out, nb);
}

// Round 8
// 189.994 us; speedup vs baseline: 1.7714x; 1.7714x over previous
//
#include <hip/hip_runtime.h>
#include <math.h>

#define NUM_IN 1024
#define TILE_R 16
#define NB_MAX 256
// prered: [8 kq][64 o][r stride 17] f32, odd multiplier kills bank conflicts
#define PR_OSTRIDE 17
#define PR_QSTRIDE (64 * PR_OSTRIDE + 4)   // 1092 f32; %32 = 4

using bf16x8 = __attribute__((ext_vector_type(8))) short;
using f32x4  = __attribute__((ext_vector_type(4))) float;

__device__ __forceinline__ unsigned int f2bf1(float f) {
  unsigned int u = __float_as_uint(f);
  return (u + 0x7fffu + ((u >> 16) & 1u)) >> 16;   // RNE f32 -> bf16
}
__device__ __forceinline__ unsigned int pk2(float a, float b) {
  return f2bf1(a) | (f2bf1(b) << 16);
}
__device__ __forceinline__ float bf2f(unsigned int s) {
  return __uint_as_float(s << 16);
}

// barrier draining LDS ops only — global loads stay in flight
#define BARX() do { \
  __builtin_amdgcn_sched_barrier(0); \
  asm volatile("s_waitcnt lgkmcnt(0)" ::: "memory"); \
  __builtin_amdgcn_s_barrier(); \
  __builtin_amdgcn_sched_barrier(0); \
} while (0)

#define WAIT_VM0() do { \
  __builtin_amdgcn_sched_barrier(0); \
  asm volatile("s_waitcnt vmcnt(0)" ::: "memory"); \
  __builtin_amdgcn_sched_barrier(0); \
} while (0)

// 256 blocks x 512 threads (8 waves). Wave w = K-slice kq (128 cols), all 4 n-tiles.
// A-fragments are built IN REGISTERS from a load pattern that matches the MFMA
// fragment layout exactly (lane l: row l&15, cols kq*128 + (l>>4)*8 + s*32).
// LDS holds only: Phase-B x-tile (bf16, dbuf, swizzled), prered, lgs.
__global__ __launch_bounds__(512, 1) void ga_main(
    const float* __restrict__ x,
    const float* __restrict__ Vw, const float* __restrict__ Uw,
    const float* __restrict__ Vb, const float* __restrict__ Ub,
    const float* __restrict__ ww, const float* __restrict__ wb,
    float* __restrict__ wsAcc, float* __restrict__ wsM, float* __restrict__ wsS,
    int nb, int nTiles)
{
  __shared__ __align__(16) unsigned short xbuf[2][TILE_R * NUM_IN];   // 64 KB bf16 dbuf
  __shared__ __align__(16) float prered[8 * PR_QSTRIDE];              // ~35 KB
  __shared__ __align__(16) float lgs[TILE_R];

  const int tid = threadIdx.x;
  const int b   = blockIdx.x;
  const int w   = tid >> 6;        // kq 0..7
  const int l   = tid & 63;
  const int l15 = l & 15;          // x-row within tile / o-sub
  const int kg  = l >> 4;          // 0..3
  const int h   = tid & 31;
  const int rr  = tid >> 5;        // act row 0..15

  const float vbh = Vb[h], ubh = Ub[h], wwh = ww[h];
  const float wb0 = wb[0];

  // ---- weights: B-frags for (all nt, this kq): 16 x uint4 = 64 VGPR ----
  // lane: o = nt*16+l15; k = w*128 + s*32 + kg*8 + i  (same (lane,i)->k map as A)
  uint4 bfr[4][4];
  {
    #pragma unroll
    for (int nt = 0; nt < 4; ++nt) {
      const int o = (nt << 4) + l15;
      const float* Wr = (o < 32) ? (Vw + (size_t)o * NUM_IN) : (Uw + (size_t)(o - 32) * NUM_IN);
      #pragma unroll
      for (int s = 0; s < 4; ++s) {
        const int k0 = (w << 7) + (s << 5) + (kg << 3);
        const float4 a = *reinterpret_cast<const float4*>(Wr + k0);
        const float4 c = *reinterpret_cast<const float4*>(Wr + k0 + 4);
        uint4 v;
        v.x = pk2(a.x, a.y); v.y = pk2(a.z, a.w);
        v.z = pk2(c.x, c.y); v.w = pk2(c.z, c.w);
        bfr[nt][s] = v;
      }
    }
    #pragma unroll
    for (int nt = 0; nt < 4; ++nt)
      #pragma unroll
      for (int s = 0; s < 4; ++s)
        asm volatile("" : "+v"(bfr[nt][s].x), "+v"(bfr[nt][s].y),
                          "+v"(bfr[nt][s].z), "+v"(bfr[nt][s].w));
  }

  const char* xb8 = (const char*)x;
  const int inRow = (w << 9) + (kg << 5);      // byte offset within a row

  float4 sA[4], sB[4];                         // 32 VGPR f32 staging
  uint4  xf[4];                                // 16 VGPR bf16 A-frags

  #define ISSUE(Tt) do { \
    const char* base_ = xb8 + ((size_t)(Tt) * TILE_R + l15) * 4096 + inRow; \
    sA[0] = *reinterpret_cast<const float4*>(base_      );  sB[0] = *reinterpret_cast<const float4*>(base_ +  16); \
    sA[1] = *reinterpret_cast<const float4*>(base_ + 128);  sB[1] = *reinterpret_cast<const float4*>(base_ + 144); \
    sA[2] = *reinterpret_cast<const float4*>(base_ + 256);  sB[2] = *reinterpret_cast<const float4*>(base_ + 272); \
    sA[3] = *reinterpret_cast<const float4*>(base_ + 384);  sB[3] = *reinterpret_cast<const float4*>(base_ + 400); \
  } while (0)

  // pack staged f32 -> A-frags (kept in regs) AND write b128 to swizzled xbuf.
  // u32 (row, cu) lives at row*2048 + (cu*4 ^ ((row&7)<<4)); swz bits 4-6 never
  // touch bits 2-3, so the b128 stays contiguous.
  #define CONVERT(bufidx) do { \
    char* dst_ = (char*)&xbuf[bufidx][0] + (l15 << 11); \
    _Pragma("unroll") \
    for (int s = 0; s < 4; ++s) { \
      uint4 v_; \
      v_.x = pk2(sA[s].x, sA[s].y); v_.y = pk2(sA[s].z, sA[s].w); \
      v_.z = pk2(sB[s].x, sB[s].y); v_.w = pk2(sB[s].z, sB[s].w); \
      xf[s] = v_; \
      const int cb_ = ((w << 8) + (s << 6) + (kg << 4)) ^ ((l15 & 7) << 4); \
      *reinterpret_cast<uint4*>(dst_ + cb_) = v_; \
    } \
    _Pragma("unroll") \
    for (int s = 0; s < 4; ++s) \
      asm volatile("" : "+v"(xf[s].x), "+v"(xf[s].y), "+v"(xf[s].z), "+v"(xf[s].w)); \
  } while (0)

  float M = -INFINITY, S = 0.f;
  float aX = 0.f, aY = 0.f;
  int cur = 0;
  int T = b;

  // ---- prologue: tile b -> frags + xbuf[0]; prime loads for b+nb ----
  ISSUE(T);
  WAIT_VM0();
  CONVERT(0);
  if (T + nb < nTiles) ISSUE(T + nb);
  BARX();

  while (true) {
    const bool more1 = (T + nb)     < nTiles;
    const bool more2 = (T + 2 * nb) < nTiles;

    // ---- P1: logit MFMAs from registers; scatter to prered ----
    {
      f32x4 acc[4] = {{0.f,0.f,0.f,0.f},{0.f,0.f,0.f,0.f},{0.f,0.f,0.f,0.f},{0.f,0.f,0.f,0.f}};
      #pragma unroll
      for (int s = 0; s < 4; ++s) {
        const bf16x8 af = __builtin_bit_cast(bf16x8, xf[s]);
        #pragma unroll
        for (int nt = 0; nt < 4; ++nt)
          acc[nt] = __builtin_amdgcn_mfma_f32_16x16x32_bf16(
              af, __builtin_bit_cast(bf16x8, bfr[nt][s]), acc[nt], 0, 0, 0);
      }
      // D: row(M=x-row) = kg*4+reg, col(N=o-sub) = l15
      #pragma unroll
      for (int nt = 0; nt < 4; ++nt) {
        const int obase = w * PR_QSTRIDE + ((nt << 4) + l15) * PR_OSTRIDE + (kg << 2);
        #pragma unroll
        for (int r = 0; r < 4; ++r) prered[obase + r] = acc[nt][r];
      }
    }
    BARX();

    // ---- P2: stage next tile (wait -> convert -> issue), then act(T) ----
    if (more1) {
      WAIT_VM0();
      CONVERT(cur ^ 1);
      if (more2) ISSUE(T + 2 * nb);
    }
    {
      float pv = vbh, pu = ubh;
      #pragma unroll
      for (int q = 0; q < 8; ++q) {
        pv += prered[q * PR_QSTRIDE + h * PR_OSTRIDE + rr];
        pu += prered[q * PR_QSTRIDE + (h + 32) * PR_OSTRIDE + rr];
      }
      const float ev = __expf(2.f * pv);
      const float av = (ev - 1.f) * __builtin_amdgcn_rcpf(ev + 1.f);   // tanh
      const float au = __builtin_amdgcn_rcpf(1.f + __expf(-pu));       // sigmoid
      float g = av * au * wwh;
      g += __shfl_xor(g, 1);
      g += __shfl_xor(g, 2);
      g += __shfl_xor(g, 4);
      g += __shfl_xor(g, 8);
      g += __shfl_xor(g, 16);
      if (h == 0) lgs[rr] = g + wb0;
    }
    BARX();

    // ---- P3: online softmax + Phase B from xbuf[cur] ----
    {
      float lf[16];
      #pragma unroll
      for (int j = 0; j < 16; ++j) lf[j] = lgs[j];
      float mc = lf[0];
      #pragma unroll
      for (int j = 1; j < 16; ++j) mc = fmaxf(mc, lf[j]);
      const float newM = fmaxf(M, mc);
      const float scale = __expf(M - newM);
      S *= scale; aX *= scale; aY *= scale;
      const char* xbsrc = (const char*)&xbuf[cur][0];
      #pragma unroll
      for (int j = 0; j < 16; ++j) {
        const float p = __expf(lf[j] - newM);
        S += p;
        const unsigned int xv = *reinterpret_cast<const unsigned int*>(
            xbsrc + (j << 11) + (((tid << 2)) ^ ((j & 7) << 4)));
        aX += p * bf2f(xv & 0xffffu);
        aY += p * bf2f(xv >> 16);
      }
      M = newM;
    }
    BARX();   // protects xbuf[cur] (overwritten by convert two phases later)

    if (!more1) break;
    cur ^= 1;
    T += nb;
  }

  *reinterpret_cast<float2*>(&wsAcc[(size_t)b * NUM_IN + (tid << 1)]) = make_float2(aX, aY);
  if (tid == 0) { wsM[b] = M; wsS[b] = S; }
}

// stage 1: global max M, weights wg_i = exp(M_i - M), total S -> wsT[0]=S
__global__ void ga_reduceMS(const float* __restrict__ wsM, const float* __restrict__ wsS,
                            float* __restrict__ wsW, float* __restrict__ wsT, int nb)
{
  __shared__ float sm[8], ss[8];
  const int t = threadIdx.x;   // 512
  float m = (t < nb) ? wsM[t] : -INFINITY;
  float mm = m;
  #pragma unroll
  for (int d = 1; d < 64; d <<= 1) mm = fmaxf(mm, __shfl_xor(mm, d));
  if ((t & 63) == 0) sm[t >> 6] = mm;
  __syncthreads();
  const float M = fmaxf(fmaxf(fmaxf(sm[0], sm[1]), fmaxf(sm[2], sm[3])),
                        fmaxf(fmaxf(sm[4], sm[5]), fmaxf(sm[6], sm[7])));
  const float wg = (t < nb) ? __expf(m - M) : 0.f;
  if (t < nb) wsW[t] = wg;
  float s = wg * ((t < nb) ? wsS[t] : 0.f);
  #pragma unroll
  for (int d = 1; d < 64; d <<= 1) s += __shfl_xor(s, d);
  if ((t & 63) == 0) ss[t >> 6] = s;
  __syncthreads();
  if (t == 0) {
    float St = 0.f;
    #pragma unroll
    for (int k = 0; k < 8; ++k) St += ss[k];
    wsT[0] = St;
  }
}

// stage 2: out[col] = (sum_i wg_i * wsAcc[i][col]) / S. 32 blocks x 32 cols.
__global__ void ga_combine(const float* __restrict__ wsAcc, const float* __restrict__ wsW,
                           const float* __restrict__ wsT, float* __restrict__ out, int nb)
{
  __shared__ float red[8][32];
  const int t = threadIdx.x;                    // 256
  const int col = (blockIdx.x << 5) + (t & 31);
  const int seg = t >> 5;                       // 0..7
  float s = 0.f;
  for (int ii = 0; ii < 64; ++ii) {
    const int i = (seg << 6) + ii;
    if (i < nb) s = fmaf(wsW[i], wsAcc[(size_t)i * NUM_IN + col], s);
  }
  red[seg][t & 31] = s;
  __syncthreads();
  if (seg == 0) {
    float tot = 0.f;
    #pragma unroll
    for (int k = 0; k < 8; ++k) tot += red[k][t];
    out[col] = tot / wsT[0];
  }
}

extern "C" void kernel_launch(void* const* d_in, const int* in_sizes, int n_in,
                              void* d_out, int out_size, void* d_ws, size_t ws_size,
                              hipStream_t stream)
{
  const float* x  = (const float*)d_in[0];
  const float* Vw = (const float*)d_in[1];
  const float* Vb = (const float*)d_in[2];
  const float* Uw = (const float*)d_in[3];
  const float* Ub = (const float*)d_in[4];
  const float* ww = (const float*)d_in[5];
  const float* wb = (const float*)d_in[6];
  float* out = (float*)d_out;

  const int Nrows  = in_sizes[0] / NUM_IN;   // 200000
  const int nTiles = Nrows / TILE_R;         // 12500

  const size_t per = (size_t)NUM_IN * 4 + 16;
  int nb = (int)((ws_size - 64) / per);
  if (nb > NB_MAX)  nb = NB_MAX;
  if (nb > nTiles)  nb = nTiles;
  if (nb < 1)       nb = 1;

  float* wsAcc = (float*)d_ws;
  float* wsM   = wsAcc + (size_t)nb * NUM_IN;
  float* wsS   = wsM + nb;
  float* wsW   = wsS + nb;
  float* wsT   = wsW + nb;

  ga_main<<<nb, 512, 0, stream>>>(x, Vw, Uw, Vb, Ub, ww, wb, wsAcc, wsM, wsS, nb, nTiles);
  ga_reduceMS<<<1, 512, 0, stream>>>(wsM, wsS, wsW, wsT, nb);
  ga_combine<<<32, 256, 0, stream>>>(wsAcc, wsW, wsT, out, nb);
}

// Round 9
// 180.507 us; speedup vs baseline: 1.8646x; 1.0526x over previous
//
#include <hip/hip_runtime.h>
#include <math.h>

#define NUM_IN 1024
#define TILE_R 16
#define NB_MAX 256
// prered: [8 kq][64 o][r stride 17] f32, odd multiplier kills bank conflicts
#define PR_OSTRIDE 17
#define PR_QSTRIDE (64 * PR_OSTRIDE + 4)   // 1092 f32; %32 = 4

using bf16x8 = __attribute__((ext_vector_type(8))) short;
using f32x4  = __attribute__((ext_vector_type(4))) float;

__device__ __forceinline__ unsigned int f2bf1(float f) {
  unsigned int u = __float_as_uint(f);
  return (u + 0x7fffu + ((u >> 16) & 1u)) >> 16;   // RNE f32 -> bf16
}
__device__ __forceinline__ unsigned int pk2(float a, float b) {
  return f2bf1(a) | (f2bf1(b) << 16);
}
__device__ __forceinline__ float bflo(unsigned int w) { return __uint_as_float(w << 16); }
__device__ __forceinline__ float bfhi(unsigned int w) { return __uint_as_float(w & 0xffff0000u); }

// barrier draining LDS ops only — global loads stay in flight
#define BARX() do { \
  __builtin_amdgcn_sched_barrier(0); \
  asm volatile("s_waitcnt lgkmcnt(0)" ::: "memory"); \
  __builtin_amdgcn_s_barrier(); \
  __builtin_amdgcn_sched_barrier(0); \
} while (0)

#define WAIT_VM0() do { \
  __builtin_amdgcn_sched_barrier(0); \
  asm volatile("s_waitcnt vmcnt(0)" ::: "memory"); \
  __builtin_amdgcn_sched_barrier(0); \
} while (0)

// 256 blocks x 512 threads (8 waves). Wave w = K-slice (128 cols), lane: row
// l15, k-group kg. A-frags AND the Phase-B weighted sum live entirely in
// registers (thread owns 32 tile elements: row l15, cols w*128+s*32+kg*8+i).
// LDS holds only prered + lgs (~35 KB). 2 barriers/iteration.
__global__ __launch_bounds__(512, 1) void ga_main(
    const float* __restrict__ x,
    const float* __restrict__ Vw, const float* __restrict__ Uw,
    const float* __restrict__ Vb, const float* __restrict__ Ub,
    const float* __restrict__ ww, const float* __restrict__ wb,
    float* __restrict__ wsAcc, float* __restrict__ wsM, float* __restrict__ wsS,
    int nb, int nTiles)
{
  __shared__ __align__(16) float prered[8 * PR_QSTRIDE];   // ~35 KB
  __shared__ __align__(16) float lgs[TILE_R];

  const int tid = threadIdx.x;
  const int b   = blockIdx.x;
  const int w   = tid >> 6;        // K-slice 0..7
  const int l   = tid & 63;
  const int l15 = l & 15;          // x-row within tile / o-sub
  const int kg  = l >> 4;          // 0..3
  const int h   = tid & 31;
  const int rr  = tid >> 5;        // act row 0..15 (within block: tid>>5 & 15)

  const float vbh = Vb[h], ubh = Ub[h], wwh = ww[h];
  const float wb0 = wb[0];

  // ---- weights: B-frags for (all nt, this w): 16 x uint4 = 64 VGPR ----
  uint4 bfr[4][4];
  {
    #pragma unroll
    for (int nt = 0; nt < 4; ++nt) {
      const int o = (nt << 4) + l15;
      const float* Wr = (o < 32) ? (Vw + (size_t)o * NUM_IN) : (Uw + (size_t)(o - 32) * NUM_IN);
      #pragma unroll
      for (int s = 0; s < 4; ++s) {
        const int k0 = (w << 7) + (s << 5) + (kg << 3);
        const float4 a = *reinterpret_cast<const float4*>(Wr + k0);
        const float4 c = *reinterpret_cast<const float4*>(Wr + k0 + 4);
        uint4 v;
        v.x = pk2(a.x, a.y); v.y = pk2(a.z, a.w);
        v.z = pk2(c.x, c.y); v.w = pk2(c.z, c.w);
        bfr[nt][s] = v;
      }
    }
    #pragma unroll
    for (int nt = 0; nt < 4; ++nt)
      #pragma unroll
      for (int s = 0; s < 4; ++s)
        asm volatile("" : "+v"(bfr[nt][s].x), "+v"(bfr[nt][s].y),
                          "+v"(bfr[nt][s].z), "+v"(bfr[nt][s].w));
  }

  const char* xb8 = (const char*)x;
  const int inRow = (w << 9) + (kg << 5);      // byte offset within a 4 KB row

  float4 sA[4], sB[4];                         // 32 VGPR f32 staging (async dest)
  uint4  xf[4];                                // 16 VGPR bf16 A-frags / Phase-B x

  #define ISSUE(Tt) do { \
    const char* base_ = xb8 + ((size_t)(Tt) * TILE_R + l15) * 4096 + inRow; \
    sA[0] = *reinterpret_cast<const float4*>(base_      );  sB[0] = *reinterpret_cast<const float4*>(base_ +  16); \
    sA[1] = *reinterpret_cast<const float4*>(base_ + 128);  sB[1] = *reinterpret_cast<const float4*>(base_ + 144); \
    sA[2] = *reinterpret_cast<const float4*>(base_ + 256);  sB[2] = *reinterpret_cast<const float4*>(base_ + 272); \
    sA[3] = *reinterpret_cast<const float4*>(base_ + 384);  sB[3] = *reinterpret_cast<const float4*>(base_ + 400); \
  } while (0)

  // pack staged f32 -> bf16 A-frags (registers only; no LDS)
  #define PACK() do { \
    _Pragma("unroll") \
    for (int s = 0; s < 4; ++s) { \
      xf[s].x = pk2(sA[s].x, sA[s].y); xf[s].y = pk2(sA[s].z, sA[s].w); \
      xf[s].z = pk2(sB[s].x, sB[s].y); xf[s].w = pk2(sB[s].z, sB[s].w); \
    } \
    _Pragma("unroll") \
    for (int s = 0; s < 4; ++s) \
      asm volatile("" : "+v"(xf[s].x), "+v"(xf[s].y), "+v"(xf[s].z), "+v"(xf[s].w)); \
  } while (0)

  float M = -INFINITY, S = 0.f;
  float acc[4][8];
  #pragma unroll
  for (int s = 0; s < 4; ++s)
    #pragma unroll
    for (int i = 0; i < 8; ++i) acc[s][i] = 0.f;

  int T = b;

  // ---- prologue ----
  ISSUE(T);
  WAIT_VM0();
  PACK();
  if (T + nb < nTiles) ISSUE(T + nb);

  while (true) {
    const bool more1 = (T + nb)     < nTiles;
    const bool more2 = (T + 2 * nb) < nTiles;

    // ---- P1: logit MFMAs from registers; scatter to prered ----
    {
      f32x4 a4[4] = {{0.f,0.f,0.f,0.f},{0.f,0.f,0.f,0.f},{0.f,0.f,0.f,0.f},{0.f,0.f,0.f,0.f}};
      #pragma unroll
      for (int s = 0; s < 4; ++s) {
        const bf16x8 af = __builtin_bit_cast(bf16x8, xf[s]);
        #pragma unroll
        for (int nt = 0; nt < 4; ++nt)
          a4[nt] = __builtin_amdgcn_mfma_f32_16x16x32_bf16(
              af, __builtin_bit_cast(bf16x8, bfr[nt][s]), a4[nt], 0, 0, 0);
      }
      // D: row(M=x-row) = kg*4+reg, col(N=o-sub) = l15
      #pragma unroll
      for (int nt = 0; nt < 4; ++nt) {
        const int obase = w * PR_QSTRIDE + ((nt << 4) + l15) * PR_OSTRIDE + (kg << 2);
        #pragma unroll
        for (int r = 0; r < 4; ++r) prered[obase + r] = a4[nt][r];
      }
    }
    BARX();

    // ---- P2: activations + per-row logit (512 threads = 16 rows x 32 h) ----
    {
      float pv = vbh, pu = ubh;
      #pragma unroll
      for (int q = 0; q < 8; ++q) {
        pv += prered[q * PR_QSTRIDE + h * PR_OSTRIDE + rr];
        pu += prered[q * PR_QSTRIDE + (h + 32) * PR_OSTRIDE + rr];
      }
      const float ev = __expf(2.f * pv);
      const float av = (ev - 1.f) * __builtin_amdgcn_rcpf(ev + 1.f);   // tanh
      const float au = __builtin_amdgcn_rcpf(1.f + __expf(-pu));       // sigmoid
      float g = av * au * wwh;
      g += __shfl_xor(g, 1);
      g += __shfl_xor(g, 2);
      g += __shfl_xor(g, 4);
      g += __shfl_xor(g, 8);
      g += __shfl_xor(g, 16);
      if (h == 0) lgs[rr] = g + wb0;
    }
    BARX();

    // ---- P3: register-resident online softmax + weighted accumulation ----
    {
      const float lf = lgs[l15];            // own row's logit
      float mc = lf;
      mc = fmaxf(mc, __shfl_xor(mc, 1));
      mc = fmaxf(mc, __shfl_xor(mc, 2));
      mc = fmaxf(mc, __shfl_xor(mc, 4));
      mc = fmaxf(mc, __shfl_xor(mc, 8));    // max over rows 0..15 (wave-uniform)
      if (mc > M) {                          // uniform branch; rare after warm-up
        const float scale = __expf(M - mc);
        S *= scale;
        #pragma unroll
        for (int s = 0; s < 4; ++s)
          #pragma unroll
          for (int i = 0; i < 8; ++i) acc[s][i] *= scale;
        M = mc;
      }
      const float p = __expf(lf - M);        // this row's softmax weight
      S += p;
      #pragma unroll
      for (int s = 0; s < 4; ++s) {
        acc[s][0] = fmaf(p, bflo(xf[s].x), acc[s][0]);
        acc[s][1] = fmaf(p, bfhi(xf[s].x), acc[s][1]);
        acc[s][2] = fmaf(p, bflo(xf[s].y), acc[s][2]);
        acc[s][3] = fmaf(p, bfhi(xf[s].y), acc[s][3]);
        acc[s][4] = fmaf(p, bflo(xf[s].z), acc[s][4]);
        acc[s][5] = fmaf(p, bfhi(xf[s].z), acc[s][5]);
        acc[s][6] = fmaf(p, bflo(xf[s].w), acc[s][6]);
        acc[s][7] = fmaf(p, bfhi(xf[s].w), acc[s][7]);
      }
      // stage next tile into registers (loads issued a full iteration ago)
      if (more1) {
        WAIT_VM0();
        PACK();
        if (more2) ISSUE(T + 2 * nb);
      }
    }

    if (!more1) break;
    T += nb;
  }

  // ---- epilogue: butterfly-sum acc & S over the 16-lane row group ----
  #pragma unroll
  for (int d = 1; d < 16; d <<= 1) {
    #pragma unroll
    for (int s = 0; s < 4; ++s)
      #pragma unroll
      for (int i = 0; i < 8; ++i) acc[s][i] += __shfl_xor(acc[s][i], d);
    S += __shfl_xor(S, d);
  }
  if (l15 == 0) {   // one lane per (w,kg): owns cols w*128 + s*32 + kg*8 + 0..7
    #pragma unroll
    for (int s = 0; s < 4; ++s) {
      float* dst = &wsAcc[(size_t)b * NUM_IN + (w << 7) + (s << 5) + (kg << 3)];
      *reinterpret_cast<float4*>(dst)     = make_float4(acc[s][0], acc[s][1], acc[s][2], acc[s][3]);
      *reinterpret_cast<float4*>(dst + 4) = make_float4(acc[s][4], acc[s][5], acc[s][6], acc[s][7]);
    }
  }
  if (tid == 0) { wsM[b] = M; wsS[b] = S; }
}

// stage 1: global max M, weights wg_i = exp(M_i - M), total S -> wsT[0]=S
__global__ void ga_reduceMS(const float* __restrict__ wsM, const float* __restrict__ wsS,
                            float* __restrict__ wsW, float* __restrict__ wsT, int nb)
{
  __shared__ float sm[8], ss[8];
  const int t = threadIdx.x;   // 512
  float m = (t < nb) ? wsM[t] : -INFINITY;
  float mm = m;
  #pragma unroll
  for (int d = 1; d < 64; d <<= 1) mm = fmaxf(mm, __shfl_xor(mm, d));
  if ((t & 63) == 0) sm[t >> 6] = mm;
  __syncthreads();
  const float M = fmaxf(fmaxf(fmaxf(sm[0], sm[1]), fmaxf(sm[2], sm[3])),
                        fmaxf(fmaxf(sm[4], sm[5]), fmaxf(sm[6], sm[7])));
  const float wg = (t < nb) ? __expf(m - M) : 0.f;
  if (t < nb) wsW[t] = wg;
  float s = wg * ((t < nb) ? wsS[t] : 0.f);
  #pragma unroll
  for (int d = 1; d < 64; d <<= 1) s += __shfl_xor(s, d);
  if ((t & 63) == 0) ss[t >> 6] = s;
  __syncthreads();
  if (t == 0) {
    float St = 0.f;
    #pragma unroll
    for (int k = 0; k < 8; ++k) St += ss[k];
    wsT[0] = St;
  }
}

// stage 2: out[col] = (sum_i wg_i * wsAcc[i][col]) / S. 32 blocks x 32 cols.
__global__ void ga_combine(const float* __restrict__ wsAcc, const float* __restrict__ wsW,
                           const float* __restrict__ wsT, float* __restrict__ out, int nb)
{
  __shared__ float red[8][32];
  const int t = threadIdx.x;                    // 256
  const int col = (blockIdx.x << 5) + (t & 31);
  const int seg = t >> 5;                       // 0..7
  float s = 0.f;
  for (int ii = 0; ii < 64; ++ii) {
    const int i = (seg << 6) + ii;
    if (i < nb) s = fmaf(wsW[i], wsAcc[(size_t)i * NUM_IN + col], s);
  }
  red[seg][t & 31] = s;
  __syncthreads();
  if (seg == 0) {
    float tot = 0.f;
    #pragma unroll
    for (int k = 0; k < 8; ++k) tot += red[k][t];
    out[col] = tot / wsT[0];
  }
}

extern "C" void kernel_launch(void* const* d_in, const int* in_sizes, int n_in,
                              void* d_out, int out_size, void* d_ws, size_t ws_size,
                              hipStream_t stream)
{
  const float* x  = (const float*)d_in[0];
  const float* Vw = (const float*)d_in[1];
  const float* Vb = (const float*)d_in[2];
  const float* Uw = (const float*)d_in[3];
  const float* Ub = (const float*)d_in[4];
  const float* ww = (const float*)d_in[5];
  const float* wb = (const float*)d_in[6];
  float* out = (float*)d_out;

  const int Nrows  = in_sizes[0] / NUM_IN;   // 200000
  const int nTiles = Nrows / TILE_R;         // 12500

  const size_t per = (size_t)NUM_IN * 4 + 16;
  int nb = (int)((ws_size - 64) / per);
  if (nb > NB_MAX)  nb = NB_MAX;
  if (nb > nTiles)  nb = nTiles;
  if (nb < 1)       nb = 1;

  float* wsAcc = (float*)d_ws;
  float* wsM   = wsAcc + (size_t)nb * NUM_IN;
  float* wsS   = wsM + nb;
  float* wsW   = wsS + nb;
  float* wsT   = wsW + nb;

  ga_main<<<nb, 512, 0, stream>>>(x, Vw, Uw, Vb, Ub, ww, wb, wsAcc, wsM, wsS, nb, nTiles);
  ga_reduceMS<<<1, 512, 0, stream>>>(wsM, wsS, wsW, wsT, nb);
  ga_combine<<<32, 256, 0, stream>>>(wsAcc, wsW, wsT, out, nb);
}

// Round 10
// 174.247 us; speedup vs baseline: 1.9315x; 1.0359x over previous
//
#include <hip/hip_runtime.h>
#include <math.h>

#define NUM_IN 1024
#define TILE_R 16
#define NB_MAX 256
// prered: [8 kq][64 o][r stride 17] f32, odd multiplier kills bank conflicts
#define PR_OSTRIDE 17
#define PR_QSTRIDE (64 * PR_OSTRIDE + 4)   // 1092 f32; %32 = 4

using bf16x8 = __attribute__((ext_vector_type(8))) short;
using f32x4  = __attribute__((ext_vector_type(4))) float;

__device__ __forceinline__ unsigned int f2bf1(float f) {
  unsigned int u = __float_as_uint(f);
  return (u + 0x7fffu + ((u >> 16) & 1u)) >> 16;   // RNE f32 -> bf16
}
__device__ __forceinline__ unsigned int pk2(float a, float b) {
  return f2bf1(a) | (f2bf1(b) << 16);
}
__device__ __forceinline__ float bflo(unsigned int w) { return __uint_as_float(w << 16); }
__device__ __forceinline__ float bfhi(unsigned int w) { return __uint_as_float(w & 0xffff0000u); }

// barrier draining LDS ops only — global loads stay in flight
#define BARX() do { \
  __builtin_amdgcn_sched_barrier(0); \
  asm volatile("s_waitcnt lgkmcnt(0)" ::: "memory"); \
  __builtin_amdgcn_s_barrier(); \
  __builtin_amdgcn_sched_barrier(0); \
} while (0)

#define WAIT_VM(n) do { \
  __builtin_amdgcn_sched_barrier(0); \
  asm volatile("s_waitcnt vmcnt(" #n ")" ::: "memory"); \
  __builtin_amdgcn_sched_barrier(0); \
} while (0)

// 256 blocks x 512 threads (8 waves). Wave w = K-slice (128 cols); lane: row
// l15, k-group kg. A-frags + Phase-B weighted sum fully register-resident.
// 2-deep staging (set0/set1), counted vmcnt(8): per-wave outstanding VMEM
// oscillates 8<->16, never 0 -> HBM base latency hidden every iteration.
__global__ __launch_bounds__(512, 1) void ga_main(
    const float* __restrict__ x,
    const float* __restrict__ Vw, const float* __restrict__ Uw,
    const float* __restrict__ Vb, const float* __restrict__ Ub,
    const float* __restrict__ ww, const float* __restrict__ wb,
    float* __restrict__ wsAcc, float* __restrict__ wsM, float* __restrict__ wsS,
    int nb, int nTiles)
{
  __shared__ __align__(16) float prered[8 * PR_QSTRIDE];   // ~35 KB
  __shared__ __align__(16) float lgs[TILE_R];

  const int tid = threadIdx.x;
  const int b   = blockIdx.x;
  const int w   = tid >> 6;        // K-slice 0..7
  const int l   = tid & 63;
  const int l15 = l & 15;          // x-row within tile / o-sub
  const int kg  = l >> 4;          // 0..3
  const int h   = tid & 31;
  const int rr  = tid >> 5;        // act row 0..15

  const float vbh = Vb[h], ubh = Ub[h], wwh = ww[h];
  const float wb0 = wb[0];

  // ---- weights: B-frags for (all nt, this w): 16 x uint4 = 64 VGPR ----
  uint4 bfr[4][4];
  {
    #pragma unroll
    for (int nt = 0; nt < 4; ++nt) {
      const int o = (nt << 4) + l15;
      const float* Wr = (o < 32) ? (Vw + (size_t)o * NUM_IN) : (Uw + (size_t)(o - 32) * NUM_IN);
      #pragma unroll
      for (int s = 0; s < 4; ++s) {
        const int k0 = (w << 7) + (s << 5) + (kg << 3);
        const float4 a = *reinterpret_cast<const float4*>(Wr + k0);
        const float4 c = *reinterpret_cast<const float4*>(Wr + k0 + 4);
        uint4 v;
        v.x = pk2(a.x, a.y); v.y = pk2(a.z, a.w);
        v.z = pk2(c.x, c.y); v.w = pk2(c.z, c.w);
        bfr[nt][s] = v;
      }
    }
    #pragma unroll
    for (int nt = 0; nt < 4; ++nt)
      #pragma unroll
      for (int s = 0; s < 4; ++s)
        asm volatile("" : "+v"(bfr[nt][s].x), "+v"(bfr[nt][s].y),
                          "+v"(bfr[nt][s].z), "+v"(bfr[nt][s].w));
  }

  const char* xb8 = (const char*)x;
  const int inRow = (w << 9) + (kg << 5);      // byte offset within a 4 KB row

  float4 sA0[4], sB0[4], sA1[4], sB1[4];       // 64 VGPR: two staging sets
  uint4  xf[4];                                // 16 VGPR bf16 A-frags / Phase-B x

  // tail issues clamp to the last tile: uniform 8 loads/iteration on every
  // path, so the compiler's waitcnt pass resolves to vmcnt(8), never (0)
  #define ISSUE_SET(sa, sb, Tt) do { \
    const int Tc_ = ((Tt) < nTiles) ? (Tt) : (nTiles - 1); \
    const char* base_ = xb8 + ((size_t)Tc_ * TILE_R + l15) * 4096 + inRow; \
    sa[0] = *reinterpret_cast<const float4*>(base_      );  sb[0] = *reinterpret_cast<const float4*>(base_ +  16); \
    sa[1] = *reinterpret_cast<const float4*>(base_ + 128);  sb[1] = *reinterpret_cast<const float4*>(base_ + 144); \
    sa[2] = *reinterpret_cast<const float4*>(base_ + 256);  sb[2] = *reinterpret_cast<const float4*>(base_ + 272); \
    sa[3] = *reinterpret_cast<const float4*>(base_ + 384);  sb[3] = *reinterpret_cast<const float4*>(base_ + 400); \
  } while (0)

  #define PACK_SET(sa, sb) do { \
    _Pragma("unroll") \
    for (int s = 0; s < 4; ++s) { \
      xf[s].x = pk2(sa[s].x, sa[s].y); xf[s].y = pk2(sa[s].z, sa[s].w); \
      xf[s].z = pk2(sb[s].x, sb[s].y); xf[s].w = pk2(sb[s].z, sb[s].w); \
    } \
    _Pragma("unroll") \
    for (int s = 0; s < 4; ++s) \
      asm volatile("" : "+v"(xf[s].x), "+v"(xf[s].y), "+v"(xf[s].z), "+v"(xf[s].w)); \
  } while (0)

  float M = -INFINITY, S = 0.f;
  float acc[4][8];
  #pragma unroll
  for (int s = 0; s < 4; ++s)
    #pragma unroll
    for (int i = 0; i < 8; ++i) acc[s][i] = 0.f;

  int T = b;

  // P1: MFMA -> prered; P2: activations -> lgs; P3 head: softmax + acc FMA
  #define COMPUTE_TILE() do { \
    { \
      f32x4 a4[4] = {{0.f,0.f,0.f,0.f},{0.f,0.f,0.f,0.f},{0.f,0.f,0.f,0.f},{0.f,0.f,0.f,0.f}}; \
      _Pragma("unroll") \
      for (int s = 0; s < 4; ++s) { \
        const bf16x8 af = __builtin_bit_cast(bf16x8, xf[s]); \
        _Pragma("unroll") \
        for (int nt = 0; nt < 4; ++nt) \
          a4[nt] = __builtin_amdgcn_mfma_f32_16x16x32_bf16( \
              af, __builtin_bit_cast(bf16x8, bfr[nt][s]), a4[nt], 0, 0, 0); \
      } \
      _Pragma("unroll") \
      for (int nt = 0; nt < 4; ++nt) { \
        const int obase = w * PR_QSTRIDE + ((nt << 4) + l15) * PR_OSTRIDE + (kg << 2); \
        _Pragma("unroll") \
        for (int r = 0; r < 4; ++r) prered[obase + r] = a4[nt][r]; \
      } \
    } \
    BARX(); \
    { \
      float pv = vbh, pu = ubh; \
      _Pragma("unroll") \
      for (int q = 0; q < 8; ++q) { \
        pv += prered[q * PR_QSTRIDE + h * PR_OSTRIDE + rr]; \
        pu += prered[q * PR_QSTRIDE + (h + 32) * PR_OSTRIDE + rr]; \
      } \
      const float ev = __expf(2.f * pv); \
      const float av = (ev - 1.f) * __builtin_amdgcn_rcpf(ev + 1.f); \
      const float au = __builtin_amdgcn_rcpf(1.f + __expf(-pu)); \
      float g = av * au * wwh; \
      g += __shfl_xor(g, 1); \
      g += __shfl_xor(g, 2); \
      g += __shfl_xor(g, 4); \
      g += __shfl_xor(g, 8); \
      g += __shfl_xor(g, 16); \
      if (h == 0) lgs[rr] = g + wb0; \
    } \
    BARX(); \
    { \
      const float lf = lgs[l15]; \
      float mc = lf; \
      mc = fmaxf(mc, __shfl_xor(mc, 1)); \
      mc = fmaxf(mc, __shfl_xor(mc, 2)); \
      mc = fmaxf(mc, __shfl_xor(mc, 4)); \
      mc = fmaxf(mc, __shfl_xor(mc, 8)); \
      if (mc > M) { \
        const float scale = __expf(M - mc); \
        S *= scale; \
        _Pragma("unroll") \
        for (int s = 0; s < 4; ++s) \
          _Pragma("unroll") \
          for (int i = 0; i < 8; ++i) acc[s][i] *= scale; \
        M = mc; \
      } \
      const float p = __expf(lf - M); \
      S += p; \
      _Pragma("unroll") \
      for (int s = 0; s < 4; ++s) { \
        acc[s][0] = fmaf(p, bflo(xf[s].x), acc[s][0]); \
        acc[s][1] = fmaf(p, bfhi(xf[s].x), acc[s][1]); \
        acc[s][2] = fmaf(p, bflo(xf[s].y), acc[s][2]); \
        acc[s][3] = fmaf(p, bfhi(xf[s].y), acc[s][3]); \
        acc[s][4] = fmaf(p, bflo(xf[s].z), acc[s][4]); \
        acc[s][5] = fmaf(p, bfhi(xf[s].z), acc[s][5]); \
        acc[s][6] = fmaf(p, bflo(xf[s].w), acc[s][6]); \
        acc[s][7] = fmaf(p, bfhi(xf[s].w), acc[s][7]); \
      } \
    } \
  } while (0)

  // ---- prologue: tile b -> xf; prime sets with b+nb (set0) and b+2nb (set1) ----
  ISSUE_SET(sA0, sB0, T);
  WAIT_VM(0);
  PACK_SET(sA0, sB0);
  ISSUE_SET(sA0, sB0, T + nb);
  ISSUE_SET(sA1, sB1, T + 2 * nb);

  // ---- main loop, unrolled x2 (static set alternation) ----
  while (true) {
    // body A: compute tile T; next tile is in set0
    COMPUTE_TILE();
    if ((T + nb) >= nTiles) break;
    WAIT_VM(8);                        // set0 done; set1's 8 stay in flight
    PACK_SET(sA0, sB0);
    ISSUE_SET(sA0, sB0, T + 3 * nb);
    T += nb;

    // body B: compute tile T; next tile is in set1
    COMPUTE_TILE();
    if ((T + nb) >= nTiles) break;
    WAIT_VM(8);                        // set1 done; set0's 8 stay in flight
    PACK_SET(sA1, sB1);
    ISSUE_SET(sA1, sB1, T + 3 * nb);
    T += nb;
  }

  // ---- epilogue: butterfly-sum acc & S over the 16-lane row group ----
  #pragma unroll
  for (int d = 1; d < 16; d <<= 1) {
    #pragma unroll
    for (int s = 0; s < 4; ++s)
      #pragma unroll
      for (int i = 0; i < 8; ++i) acc[s][i] += __shfl_xor(acc[s][i], d);
    S += __shfl_xor(S, d);
  }
  if (l15 == 0) {   // one lane per (w,kg): owns cols w*128 + s*32 + kg*8 + 0..7
    #pragma unroll
    for (int s = 0; s < 4; ++s) {
      float* dst = &wsAcc[(size_t)b * NUM_IN + (w << 7) + (s << 5) + (kg << 3)];
      *reinterpret_cast<float4*>(dst)     = make_float4(acc[s][0], acc[s][1], acc[s][2], acc[s][3]);
      *reinterpret_cast<float4*>(dst + 4) = make_float4(acc[s][4], acc[s][5], acc[s][6], acc[s][7]);
    }
  }
  if (tid == 0) { wsM[b] = M; wsS[b] = S; }
}

// stage 1: global max M, weights wg_i = exp(M_i - M), total S -> wsT[0]=S
__global__ void ga_reduceMS(const float* __restrict__ wsM, const float* __restrict__ wsS,
                            float* __restrict__ wsW, float* __restrict__ wsT, int nb)
{
  __shared__ float sm[8], ss[8];
  const int t = threadIdx.x;   // 512
  float m = (t < nb) ? wsM[t] : -INFINITY;
  float mm = m;
  #pragma unroll
  for (int d = 1; d < 64; d <<= 1) mm = fmaxf(mm, __shfl_xor(mm, d));
  if ((t & 63) == 0) sm[t >> 6] = mm;
  __syncthreads();
  const float M = fmaxf(fmaxf(fmaxf(sm[0], sm[1]), fmaxf(sm[2], sm[3])),
                        fmaxf(fmaxf(sm[4], sm[5]), fmaxf(sm[6], sm[7])));
  const float wg = (t < nb) ? __expf(m - M) : 0.f;
  if (t < nb) wsW[t] = wg;
  float s = wg * ((t < nb) ? wsS[t] : 0.f);
  #pragma unroll
  for (int d = 1; d < 64; d <<= 1) s += __shfl_xor(s, d);
  if ((t & 63) == 0) ss[t >> 6] = s;
  __syncthreads();
  if (t == 0) {
    float St = 0.f;
    #pragma unroll
    for (int k = 0; k < 8; ++k) St += ss[k];
    wsT[0] = St;
  }
}

// stage 2: out[col] = (sum_i wg_i * wsAcc[i][col]) / S. 32 blocks x 32 cols.
__global__ void ga_combine(const float* __restrict__ wsAcc, const float* __restrict__ wsW,
                           const float* __restrict__ wsT, float* __restrict__ out, int nb)
{
  __shared__ float red[8][32];
  const int t = threadIdx.x;                    // 256
  const int col = (blockIdx.x << 5) + (t & 31);
  const int seg = t >> 5;                       // 0..7
  float s = 0.f;
  for (int ii = 0; ii < 64; ++ii) {
    const int i = (seg << 6) + ii;
    if (i < nb) s = fmaf(wsW[i], wsAcc[(size_t)i * NUM_IN + col], s);
  }
  red[seg][t & 31] = s;
  __syncthreads();
  if (seg == 0) {
    float tot = 0.f;
    #pragma unroll
    for (int k = 0; k < 8; ++k) tot += red[k][t];
    out[col] = tot / wsT[0];
  }
}

extern "C" void kernel_launch(void* const* d_in, const int* in_sizes, int n_in,
                              void* d_out, int out_size, void* d_ws, size_t ws_size,
                              hipStream_t stream)
{
  const float* x  = (const float*)d_in[0];
  const float* Vw = (const float*)d_in[1];
  const float* Vb = (const float*)d_in[2];
  const float* Uw = (const float*)d_in[3];
  const float* Ub = (const float*)d_in[4];
  const float* ww = (const float*)d_in[5];
  const float* wb = (const float*)d_in[6];
  float* out = (float*)d_out;

  const int Nrows  = in_sizes[0] / NUM_IN;   // 200000
  const int nTiles = Nrows / TILE_R;         // 12500

  const size_t per = (size_t)NUM_IN * 4 + 16;
  int nb = (int)((ws_size - 64) / per);
  if (nb > NB_MAX)  nb = NB_MAX;
  if (nb > nTiles)  nb = nTiles;
  if (nb < 1)       nb = 1;

  float* wsAcc = (float*)d_ws;
  float* wsM   = wsAcc + (size_t)nb * NUM_IN;
  float* wsS   = wsM + nb;
  float* wsW   = wsS + nb;
  float* wsT   = wsW + nb;

  ga_main<<<nb, 512, 0, stream>>>(x, Vw, Uw, Vb, Ub, ww, wb, wsAcc, wsM, wsS, nb, nTiles);
  ga_reduceMS<<<1, 512, 0, stream>>>(wsM, wsS, wsW, wsT, nb);
  ga_combine<<<32, 256, 0, stream>>>(wsAcc, wsW, wsT, out, nb);
}